// Round 1
// baseline (85.731 us; speedup 1.0000x reference)
//
#include <hip/hip_runtime.h>

#define NB_C 512
#define NB_B 1024
#define SB_RED 32   // B-splits for reduce kernel (32 rows per block)
#define SB_NRM 32   // B-splits for normalize kernel

// Decode window-linear index wl in [0,36) -> (l, w); returns l, sets w.
// cumM = {0,1,4,9,16,25,36} (cumsum of M=2l+1). Note cumM[l] = wl - w.
__device__ __forceinline__ int decode_lw(int wl, int& w) {
  if (wl < 1)  { w = wl;      return 0; }
  if (wl < 4)  { w = wl - 1;  return 1; }
  if (wl < 9)  { w = wl - 4;  return 2; }
  if (wl < 16) { w = wl - 9;  return 3; }
  if (wl < 25) { w = wl - 16; return 4; }
  w = wl - 25; return 5;
}

__device__ __forceinline__ const float4* pick_f(int l,
    const float4* f0, const float4* f1, const float4* f2,
    const float4* f3, const float4* f4, const float4* f5) {
  switch (l) {
    case 0: return f0; case 1: return f1; case 2: return f2;
    case 3: return f3; case 4: return f4; default: return f5;
  }
}

// Pass 1: per-channel sum(norm), sum(norm^2) via private accumulation over
// the B dimension (each thread's channel assignment is loop-invariant),
// then LDS segmented reduce + one global atomicAdd per (block, channel).
__global__ __launch_bounds__(256)
void bn_reduce(const float4* __restrict__ f0, const float4* __restrict__ f1,
               const float4* __restrict__ f2, const float4* __restrict__ f3,
               const float4* __restrict__ f4, const float4* __restrict__ f5,
               float* __restrict__ gsum, float* __restrict__ gsq)
{
  const int bs = blockIdx.x % SB_RED;
  const int wl = blockIdx.x / SB_RED;
  int w; const int l = decode_lw(wl, w);
  const int M = 2 * l + 1;
  const float4* __restrict__ f = pick_f(l, f0, f1, f2, f3, f4, f5);

  const int t  = threadIdx.x;
  const int o4 = w * 256 + t;          // float4 offset within a row
  const int e0 = 2 * o4;               // float2 (=one [x,y] pair) index
  const int c0 = e0 / M;               // channel of pair 0 (loop-invariant)
  const int c1 = (e0 + 1) / M;         // channel of pair 1
  const int rs4 = 256 * M;             // row stride in float4
  const int Bc  = NB_B / SB_RED;

  const float4* p = f + (size_t)(bs * Bc) * rs4 + o4;
  float s0 = 0.f, q0 = 0.f, s1 = 0.f, q1 = 0.f;
#pragma unroll 4
  for (int i = 0; i < Bc; ++i) {
    float4 v = p[(size_t)i * rs4];
    float r0 = v.x * v.x + v.y * v.y;
    float r1 = v.z * v.z + v.w * v.w;
    s0 += sqrtf(r0); q0 += r0;
    s1 += sqrtf(r1); q1 += r1;
  }

  __shared__ float ls[512];
  __shared__ float lq[512];
  __shared__ short lc[512];
  ls[2*t]   = s0; lq[2*t]   = q0; lc[2*t]   = (short)c0;
  ls[2*t+1] = s1; lq[2*t+1] = q1; lc[2*t+1] = (short)c1;
  __syncthreads();

  const int base = l * NB_C;
#pragma unroll
  for (int k = 0; k < 2; ++k) {
    const int e = 2 * t + k;
    const short c = lc[e];
    if (e == 0 || lc[e-1] != c) {       // segment leader
      float a = 0.f, a2 = 0.f;
      int j = e;
      while (j < 512 && lc[j] == c) { a += ls[j]; a2 += lq[j]; ++j; }
      atomicAdd(&gsum[base + (int)c], a);
      atomicAdd(&gsq [base + (int)c], a2);
    }
  }
}

// Pass 2: 3072 channels -> reciprocal scale.
__global__ __launch_bounds__(256)
void bn_finalize(const float* __restrict__ gsum, const float* __restrict__ gsq,
                 const float* __restrict__ s0, const float* __restrict__ s1,
                 const float* __restrict__ s2, const float* __restrict__ s3,
                 const float* __restrict__ s4, const float* __restrict__ s5,
                 float* __restrict__ sinv)
{
  const int ch = blockIdx.x * 256 + threadIdx.x;
  if (ch >= 6 * NB_C) return;
  const int l = ch >> 9;
  const int c = ch & (NB_C - 1);
  const float cnt = (float)(NB_B * (2 * l + 1));
  const float mean = gsum[ch] / cnt;
  const float var  = fmaxf(gsq[ch] / cnt - mean * mean, 0.f);
  const float bstd = sqrtf(var);
  const float* sp;
  switch (l) {
    case 0: sp = s0; break; case 1: sp = s1; break; case 2: sp = s2; break;
    case 3: sp = s3; break; case 4: sp = s4; break; default: sp = s5; break;
  }
  const float nstd = 0.5f * (sp[c] + bstd);   // CNT=1: std/2 + bstd/2
  sinv[ch] = 1.0f / fmaxf(1e-5f, nstd);
}

// Pass 3: out = f * sinv[channel], float4 in / float4 out.
__global__ __launch_bounds__(256)
void bn_norm(const float4* __restrict__ f0, const float4* __restrict__ f1,
             const float4* __restrict__ f2, const float4* __restrict__ f3,
             const float4* __restrict__ f4, const float4* __restrict__ f5,
             const float* __restrict__ sinv, float4* __restrict__ out)
{
  const int bs = blockIdx.x % SB_NRM;
  const int wl = blockIdx.x / SB_NRM;
  int w; const int l = decode_lw(wl, w);
  const int cumM = wl - w;             // cumsum of M below l
  const int M = 2 * l + 1;
  const float4* __restrict__ f = pick_f(l, f0, f1, f2, f3, f4, f5);

  const int t  = threadIdx.x;
  const int o4 = w * 256 + t;
  const int e0 = 2 * o4;
  const int c0 = e0 / M;
  const int c1 = (e0 + 1) / M;
  const float sc0 = sinv[l * NB_C + c0];
  const float sc1 = sinv[l * NB_C + c1];
  const int rs4 = 256 * M;
  const int Bc  = NB_B / SB_NRM;

  // per-l output base in float4: 1024*512*M*2/4 = 262144*M, cumulative.
  const size_t ob = (size_t)262144 * cumM;
  const size_t tb = (size_t)(bs * Bc) * rs4 + o4;
  const float4* p = f + tb;
  float4* q = out + ob + tb;
#pragma unroll 4
  for (int i = 0; i < Bc; ++i) {
    float4 v = p[(size_t)i * rs4];
    v.x *= sc0; v.y *= sc0; v.z *= sc1; v.w *= sc1;
    q[(size_t)i * rs4] = v;
  }
}

extern "C" void kernel_launch(void* const* d_in, const int* in_sizes, int n_in,
                              void* d_out, int out_size, void* d_ws, size_t ws_size,
                              hipStream_t stream) {
  const float4* f[6];
  const float* s[6];
  for (int l = 0; l < 6; ++l) {
    f[l] = (const float4*)d_in[l];
    s[l] = (const float*)d_in[6 + l];
  }
  float* gsum = (float*)d_ws;          // 3072 floats
  float* gsq  = gsum + 6 * NB_C;       // 3072 floats
  float* sinv = gsq + 6 * NB_C;        // 3072 floats

  hipMemsetAsync(gsum, 0, 2 * 6 * NB_C * sizeof(float), stream);

  bn_reduce<<<36 * SB_RED, 256, 0, stream>>>(
      f[0], f[1], f[2], f[3], f[4], f[5], gsum, gsq);
  bn_finalize<<<12, 256, 0, stream>>>(
      gsum, gsq, s[0], s[1], s[2], s[3], s[4], s[5], sinv);
  bn_norm<<<36 * SB_NRM, 256, 0, stream>>>(
      f[0], f[1], f[2], f[3], f[4], f[5], sinv, (float4*)d_out);
}

// Round 3
// 81.724 us; speedup vs baseline: 1.0490x; 1.0490x over previous
//
#include <hip/hip_runtime.h>

#define NB_C 512
#define NB_B 1024
#define SB_RED 32   // B-splits for reduce kernel (32 rows per block)
#define SB_NRM 32   // B-splits for normalize kernel

typedef float vf4 __attribute__((ext_vector_type(4)));

// Decode window-linear index wl in [0,36) -> (l, w); returns l, sets w.
// cumM = {0,1,4,9,16,25,36} (cumsum of M=2l+1). Note cumM[l] = wl - w.
__device__ __forceinline__ int decode_lw(int wl, int& w) {
  if (wl < 1)  { w = wl;      return 0; }
  if (wl < 4)  { w = wl - 1;  return 1; }
  if (wl < 9)  { w = wl - 4;  return 2; }
  if (wl < 16) { w = wl - 9;  return 3; }
  if (wl < 25) { w = wl - 16; return 4; }
  w = wl - 25; return 5;
}

__device__ __forceinline__ const vf4* pick_f(int l,
    const vf4* f0, const vf4* f1, const vf4* f2,
    const vf4* f3, const vf4* f4, const vf4* f5) {
  switch (l) {
    case 0: return f0; case 1: return f1; case 2: return f2;
    case 3: return f3; case 4: return f4; default: return f5;
  }
}

__device__ __forceinline__ const float* pick_s(int l,
    const float* s0, const float* s1, const float* s2,
    const float* s3, const float* s4, const float* s5) {
  switch (l) {
    case 0: return s0; case 1: return s1; case 2: return s2;
    case 3: return s3; case 4: return s4; default: return s5;
  }
}

// Pass 1: per-channel sum(norm), sum(norm^2) via private accumulation over
// the B dimension (each thread's channel assignment is loop-invariant),
// then LDS segmented reduce + one global atomicAdd per (block, channel).
// Regular (caching) loads on purpose: they populate L3 for pass 2.
__global__ __launch_bounds__(256)
void bn_reduce(const vf4* __restrict__ f0, const vf4* __restrict__ f1,
               const vf4* __restrict__ f2, const vf4* __restrict__ f3,
               const vf4* __restrict__ f4, const vf4* __restrict__ f5,
               float* __restrict__ gsum, float* __restrict__ gsq)
{
  const int bs = blockIdx.x % SB_RED;
  const int wl = blockIdx.x / SB_RED;
  int w; const int l = decode_lw(wl, w);
  const int M = 2 * l + 1;
  const vf4* __restrict__ f = pick_f(l, f0, f1, f2, f3, f4, f5);

  const int t  = threadIdx.x;
  const int o4 = w * 256 + t;          // float4 offset within a row
  const int e0 = 2 * o4;               // float2 (=one [x,y] pair) index
  const int c0 = e0 / M;               // channel of pair 0 (loop-invariant)
  const int c1 = (e0 + 1) / M;         // channel of pair 1
  const int rs4 = 256 * M;             // row stride in float4
  const int Bc  = NB_B / SB_RED;

  const vf4* p = f + (size_t)(bs * Bc) * rs4 + o4;
  float s0 = 0.f, q0 = 0.f, s1 = 0.f, q1 = 0.f;
#pragma unroll 8
  for (int i = 0; i < Bc; ++i) {
    vf4 v = p[(size_t)i * rs4];
    float r0 = v.x * v.x + v.y * v.y;
    float r1 = v.z * v.z + v.w * v.w;
    s0 += sqrtf(r0); q0 += r0;
    s1 += sqrtf(r1); q1 += r1;
  }

  __shared__ float ls[512];
  __shared__ float lq[512];
  __shared__ short lc[512];
  ls[2*t]   = s0; lq[2*t]   = q0; lc[2*t]   = (short)c0;
  ls[2*t+1] = s1; lq[2*t+1] = q1; lc[2*t+1] = (short)c1;
  __syncthreads();

  const int base = l * NB_C;
#pragma unroll
  for (int k = 0; k < 2; ++k) {
    const int e = 2 * t + k;
    const short c = lc[e];
    if (e == 0 || lc[e-1] != c) {       // segment leader
      float a = 0.f, a2 = 0.f;
      int j = e;
      while (j < 512 && lc[j] == c) { a += ls[j]; a2 += lq[j]; ++j; }
      atomicAdd(&gsum[base + (int)c], a);
      atomicAdd(&gsq [base + (int)c], a2);
    }
  }
}

// Compute reciprocal scale for one channel from the accumulated moments.
__device__ __forceinline__ float chan_scale(float sum, float sq, float rstd,
                                            float cnt) {
  const float mean = sum / cnt;
  const float var  = fmaxf(sq / cnt - mean * mean, 0.f);
  const float bstd = sqrtf(var);
  const float nstd = 0.5f * (rstd + bstd);   // CNT=1: std/2 + bstd/2
  return 1.0f / fmaxf(1e-5f, nstd);
}

// Pass 2: out = f * sinv[channel], float4 in / nt float4 out.
// Finalize is inlined (3 cached scalar loads per thread); output stores are
// non-temporal so the 151 MB write stream doesn't evict the L3-resident input.
__global__ __launch_bounds__(256)
void bn_norm(const vf4* __restrict__ f0, const vf4* __restrict__ f1,
             const vf4* __restrict__ f2, const vf4* __restrict__ f3,
             const vf4* __restrict__ f4, const vf4* __restrict__ f5,
             const float* __restrict__ s0, const float* __restrict__ s1,
             const float* __restrict__ s2, const float* __restrict__ s3,
             const float* __restrict__ s4, const float* __restrict__ s5,
             const float* __restrict__ gsum, const float* __restrict__ gsq,
             vf4* __restrict__ out)
{
  const int bs = blockIdx.x % SB_NRM;
  const int wl = blockIdx.x / SB_NRM;
  int w; const int l = decode_lw(wl, w);
  const int cumM = wl - w;             // cumsum of M below l
  const int M = 2 * l + 1;
  const vf4* __restrict__ f = pick_f(l, f0, f1, f2, f3, f4, f5);
  const float* __restrict__ sp = pick_s(l, s0, s1, s2, s3, s4, s5);

  const int t  = threadIdx.x;
  const int o4 = w * 256 + t;
  const int e0 = 2 * o4;
  const int c0 = e0 / M;
  const int c1 = (e0 + 1) / M;
  const int base = l * NB_C;
  const float cnt = (float)(NB_B * M);
  const float sc0 = chan_scale(gsum[base + c0], gsq[base + c0], sp[c0], cnt);
  const float sc1 = chan_scale(gsum[base + c1], gsq[base + c1], sp[c1], cnt);
  const int rs4 = 256 * M;
  const int Bc  = NB_B / SB_NRM;

  // per-l output base in float4: 1024*512*M*2/4 = 262144*M, cumulative.
  const size_t ob = (size_t)262144 * cumM;
  const size_t tb = (size_t)(bs * Bc) * rs4 + o4;
  const vf4* p = f + tb;
  vf4* q = out + ob + tb;
#pragma unroll 8
  for (int i = 0; i < Bc; ++i) {
    vf4 v = p[(size_t)i * rs4];
    v.x *= sc0; v.y *= sc0; v.z *= sc1; v.w *= sc1;
    __builtin_nontemporal_store(v, &q[(size_t)i * rs4]);
  }
}

extern "C" void kernel_launch(void* const* d_in, const int* in_sizes, int n_in,
                              void* d_out, int out_size, void* d_ws, size_t ws_size,
                              hipStream_t stream) {
  const vf4* f[6];
  const float* s[6];
  for (int l = 0; l < 6; ++l) {
    f[l] = (const vf4*)d_in[l];
    s[l] = (const float*)d_in[6 + l];
  }
  float* gsum = (float*)d_ws;          // 3072 floats
  float* gsq  = gsum + 6 * NB_C;       // 3072 floats

  (void)hipMemsetAsync(gsum, 0, 2 * 6 * NB_C * sizeof(float), stream);

  bn_reduce<<<36 * SB_RED, 256, 0, stream>>>(
      f[0], f[1], f[2], f[3], f[4], f[5], gsum, gsq);
  bn_norm<<<36 * SB_NRM, 256, 0, stream>>>(
      f[0], f[1], f[2], f[3], f[4], f[5],
      s[0], s[1], s[2], s[3], s[4], s[5],
      gsum, gsq, (vf4*)d_out);
}